// Round 4
// baseline (238.129 us; speedup 1.0000x reference)
//
#include <hip/hip_runtime.h>
#include <hip/hip_bf16.h>

#define H 4
#define NQ 4096
#define NK 8192
#define D 64
#define BK 64
#define LDK 72
#define NSPLIT 4
#define KSPAN (NK / NSPLIT)

// 0.125 (1/sqrt(64)) * log2(e): scores emerge in log2 domain
#define QSCALE 0.1803368801111204f
#define MFIX 8.0f  // fixed softmax "max": |S| hard-bounded ~12, exp2(S-8) can't overflow

typedef short v8s __attribute__((ext_vector_type(8)));
typedef float v4f __attribute__((ext_vector_type(4)));

static __device__ __forceinline__ unsigned short f2bf(float f) {
    unsigned int u = __float_as_uint(f);
    u = (u + 0x7FFFu + ((u >> 16) & 1u)) >> 16;
    return (unsigned short)u;
}
static __device__ __forceinline__ float bf2f(unsigned short h) {
    return __uint_as_float(((unsigned int)h) << 16);
}
static __device__ __forceinline__ unsigned int pkbf(float a, float b) {
    union { __hip_bfloat162 h; unsigned int u; } cv;
    cv.h = __float22bfloat162_rn(make_float2(a, b));
    return cv.u;
}
static __device__ __forceinline__ void split8(const float* a, v8s& hi, v8s& lo) {
#pragma unroll
    for (int j = 0; j < 8; ++j) {
        unsigned short h = f2bf(a[j]);
        hi[j] = (short)h;
        lo[j] = (short)f2bf(a[j] - bf2f(h));
    }
}

// ---- W prep: bf16 hi/lo planes, TRANSPOSED [col][k]
__global__ __launch_bounds__(256) void wprep_kernel(
    const float* __restrict__ Wq, const float* __restrict__ Wk,
    const float* __restrict__ Wv, const float* __restrict__ Wo,
    unsigned short* __restrict__ Wqt, unsigned short* __restrict__ Wkt,
    unsigned short* __restrict__ Wvt, unsigned short* __restrict__ Wot)
{
    int i = blockIdx.x * 256 + threadIdx.x;
    const float* src; unsigned short* dst; int idx, sh;
    if (i < 65536)       { src = Wq; dst = Wqt; idx = i;          sh = 8; }
    else if (i < 81920)  { src = Wk; dst = Wkt; idx = i - 65536;  sh = 6; }
    else if (i < 98304)  { src = Wv; dst = Wvt; idx = i - 81920;  sh = 6; }
    else                 { src = Wo; dst = Wot; idx = i - 98304;  sh = 8; }
    const int K = 1 << sh;
    const int c = idx >> sh, e = idx & (K - 1);
    const float v = src[e * 256 + c];
    const unsigned short h = f2bf(v);
    dst[idx] = h;
    dst[idx + (K << 8)] = f2bf(v - bf2f(h));
}

// ---- shared projection GEMM: 16 rows x 64 cols per wave, hi/lo 3-MFMA
template <int KD>
static __device__ __forceinline__ void proj_gemm(
    const float* __restrict__ X, const unsigned short* __restrict__ Wt,
    const float* __restrict__ bias, int n0, int colbase, int l16, int quad,
    v4f acc[4])
{
#pragma unroll
    for (int ct = 0; ct < 4; ++ct) {
        const float b = bias[colbase + ct * 16 + l16];
        acc[ct] = v4f{b, b, b, b};
    }
    const float* arow = X + (size_t)(n0 + l16) * KD + quad * 8;
#pragma unroll
    for (int k0 = 0; k0 < KD; k0 += 32) {
        float av[8];
        *(float4*)av = *(const float4*)(arow + k0);
        *(float4*)(av + 4) = *(const float4*)(arow + k0 + 4);
        v8s ah, al;
        split8(av, ah, al);
#pragma unroll
        for (int ct = 0; ct < 4; ++ct) {
            const unsigned short* wp = Wt + (size_t)(colbase + ct * 16 + l16) * KD + k0 + quad * 8;
            const v8s wh = *(const v8s*)wp;
            const v8s wl = *(const v8s*)(wp + KD * 256);
            acc[ct] = __builtin_amdgcn_mfma_f32_16x16x32_bf16(al, wh, acc[ct], 0, 0, 0);
            acc[ct] = __builtin_amdgcn_mfma_f32_16x16x32_bf16(ah, wl, acc[ct], 0, 0, 0);
            acc[ct] = __builtin_amdgcn_mfma_f32_16x16x32_bf16(ah, wh, acc[ct], 0, 0, 0);
        }
    }
}

// ---- fused Q/K/V projection: blocks [0,512) Q, [512,1536) K, [1536,2560) V
__global__ __launch_bounds__(128) void qkv_kernel(
    const float* __restrict__ query, const float* __restrict__ key,
    const float* __restrict__ value,
    const unsigned short* __restrict__ Wqt, const unsigned short* __restrict__ Wkt,
    const unsigned short* __restrict__ Wvt,
    const float* __restrict__ bq, const float* __restrict__ bk,
    const float* __restrict__ bv,
    unsigned short* __restrict__ Qb, unsigned short* __restrict__ Kb,
    unsigned short* __restrict__ Vt, const int* __restrict__ nexp)
{
    const int b = blockIdx.x;
    const int t = threadIdx.x, w = t >> 6, lane = t & 63;
    const int quad = lane >> 4, l16 = lane & 15;
    v4f acc[4];
    if (b < 512) {
        const int n0 = (b >> 1) * 16, colbase = (b & 1) * 128 + w * 64;
        proj_gemm<256>(query, Wqt, bq, n0, colbase, l16, quad, acc);
        const int hidx = colbase >> 6;
#pragma unroll
        for (int ct = 0; ct < 4; ++ct) {
            const int d = ct * 16 + l16;
            const int j = d >> 1;
            const float freq = exp2f(-(float)(j & 15) * 1.66096404744368f);
            const bool isx = (j < 16), odd = (d & 1);
#pragma unroll
            for (int r = 0; r < 4; ++r) {
                const int p = n0 + quad * 4 + r;
                const float tpos = isx ? (float)(p & 63) : (float)(p >> 6);
                float sn, cs;
                __sincosf(tpos * freq, &sn, &cs);
                const float x = acc[ct][r];
                const float xp = __shfl_xor(x, 1, 64);
                const float y = odd ? fmaf(x, cs, xp * sn) : fmaf(x, cs, -xp * sn);
                Qb[((size_t)(hidx * NQ + p) << 6) + d] = f2bf(y * QSCALE);
            }
        }
    } else if (b < 1536) {
        const int b2 = b - 512;
        const int n0 = (b2 >> 1) * 16, colbase = (b2 & 1) * 128 + w * 64;
        proj_gemm<64>(key, Wkt, bk, n0, colbase, l16, quad, acc);
        const int nro = NK - *nexp;
        const int hidx = colbase >> 6;
#pragma unroll
        for (int ct = 0; ct < 4; ++ct) {
            const int d = ct * 16 + l16;
            const int j = d >> 1;
            const float freq = exp2f(-(float)(j & 15) * 1.66096404744368f);
            const bool isx = (j < 16), odd = (d & 1);
#pragma unroll
            for (int r = 0; r < 4; ++r) {
                const int p = n0 + quad * 4 + r;
                const int pc = p & 4095;
                const float tpos = isx ? (float)(pc & 63) : (float)(pc >> 6);
                float sn, cs;
                __sincosf(tpos * freq, &sn, &cs);
                const float x = acc[ct][r];
                const float xp = __shfl_xor(x, 1, 64);
                float y = odd ? fmaf(x, cs, xp * sn) : fmaf(x, cs, -xp * sn);
                y = (p < nro) ? y : x;
                Kb[((size_t)(hidx * NK + p) << 6) + d] = f2bf(y);
            }
        }
    } else {
        const int b2 = b - 1536;
        const int n0 = (b2 >> 1) * 16, colbase = (b2 & 1) * 128 + w * 64;
        proj_gemm<64>(value, Wvt, bv, n0, colbase, l16, quad, acc);
#pragma unroll
        for (int ct = 0; ct < 4; ++ct) {
            const int col = colbase + ct * 16 + l16;
            uint2 u = make_uint2(pkbf(acc[ct][0], acc[ct][1]), pkbf(acc[ct][2], acc[ct][3]));
            *(uint2*)(Vt + (size_t)col * NK + n0 + quad * 4) = u;
        }
    }
}

// ---- flash attention, fixed-max, S^T/O^T form, direct-global K/V, no barriers
// 2048 single-wave blocks: blk = qt*16 + h*4 + s  (XCD-local K/V chunks)
__global__ __launch_bounds__(64) void attn_kernel(
    const unsigned short* __restrict__ Qb, const unsigned short* __restrict__ Kb,
    const unsigned short* __restrict__ Vt, float* __restrict__ Opart,
    float* __restrict__ Lbuf)
{
    __shared__ alignas(16) unsigned short Pl[32 * LDK];
    const int blk = blockIdx.x;
    const int s = blk & 3, h = (blk >> 2) & 3, qt = blk >> 4;
    const int lane = threadIdx.x, quad = lane >> 4, l16 = lane & 15;
    const int q0 = qt * 32;

    v8s qf[2][2];
#pragma unroll
    for (int g = 0; g < 2; ++g) {
        const unsigned short* qr = Qb + ((size_t)(h * NQ + q0 + g * 16 + l16) << 6) + quad * 8;
        qf[g][0] = *(const v8s*)qr;
        qf[g][1] = *(const v8s*)(qr + 32);
    }

    v4f O[4][2];
#pragma unroll
    for (int dt = 0; dt < 4; ++dt)
#pragma unroll
        for (int g = 0; g < 2; ++g) O[dt][g] = v4f{0.f, 0.f, 0.f, 0.f};
    float psum[2] = {0.f, 0.f};

    const unsigned short* Kh = Kb + ((size_t)h * NK << 6);
    const unsigned short* Vh = Vt + (size_t)(h * 64) * NK;
    const int kbeg = s * KSPAN;

    for (int k0 = kbeg; k0 < kbeg + KSPAN; k0 += BK) {
        // K fragments straight from global (lane-fixed rows; L2-resident per XCD)
        v8s kf[4][2];
#pragma unroll
        for (int tt = 0; tt < 4; ++tt) {
            const unsigned short* kr = Kh + ((size_t)(k0 + tt * 16 + l16) << 6) + quad * 8;
            kf[tt][0] = *(const v8s*)kr;
            kf[tt][1] = *(const v8s*)(kr + 32);
        }
        // V fragments straight from global (row-major in d, transposed layout)
        v8s vf[4][2];
#pragma unroll
        for (int dt = 0; dt < 4; ++dt) {
            const unsigned short* vr = Vh + (size_t)(dt * 16 + l16) * NK + k0 + quad * 8;
            vf[dt][0] = *(const v8s*)vr;
            vf[dt][1] = *(const v8s*)(vr + 32);
        }

        // S^T = K Q^T : col = q (lane), row = k (quad*4+reg)
        v4f S[4][2];
#pragma unroll
        for (int tt = 0; tt < 4; ++tt)
#pragma unroll
            for (int g = 0; g < 2; ++g) {
                v4f a = v4f{0.f, 0.f, 0.f, 0.f};
                a = __builtin_amdgcn_mfma_f32_16x16x32_bf16(kf[tt][0], qf[g][0], a, 0, 0, 0);
                a = __builtin_amdgcn_mfma_f32_16x16x32_bf16(kf[tt][1], qf[g][1], a, 0, 0, 0);
                S[tt][g] = a;
            }

        // fixed-max softmax numerator; P stored [q][k] in per-wave LDS
#pragma unroll
        for (int tt = 0; tt < 4; ++tt)
#pragma unroll
            for (int g = 0; g < 2; ++g) {
                const float e0 = __builtin_amdgcn_exp2f(S[tt][g][0] - MFIX);
                const float e1 = __builtin_amdgcn_exp2f(S[tt][g][1] - MFIX);
                const float e2 = __builtin_amdgcn_exp2f(S[tt][g][2] - MFIX);
                const float e3 = __builtin_amdgcn_exp2f(S[tt][g][3] - MFIX);
                psum[g] += (e0 + e1) + (e2 + e3);
                *(uint2*)(&Pl[(g * 16 + l16) * LDK + tt * 16 + quad * 4]) =
                    make_uint2(pkbf(e0, e1), pkbf(e2, e3));
            }
        __asm__ volatile("s_waitcnt lgkmcnt(0)" ::: "memory");

        // O^T += V^T P^T : col = q (lane) — matches psum lane, no broadcasts
        v8s pf[2][2];
#pragma unroll
        for (int g = 0; g < 2; ++g) {
            const unsigned short* pr = &Pl[(g * 16 + l16) * LDK + quad * 8];
            pf[g][0] = *(const v8s*)pr;
            pf[g][1] = *(const v8s*)(pr + 32);
        }
#pragma unroll
        for (int dt = 0; dt < 4; ++dt)
#pragma unroll
            for (int g = 0; g < 2; ++g) {
                v4f a = O[dt][g];
                a = __builtin_amdgcn_mfma_f32_16x16x32_bf16(vf[dt][0], pf[g][0], a, 0, 0, 0);
                a = __builtin_amdgcn_mfma_f32_16x16x32_bf16(vf[dt][1], pf[g][1], a, 0, 0, 0);
                O[dt][g] = a;
            }
    }

#pragma unroll
    for (int g = 0; g < 2; ++g) {
        float p = psum[g];
        p += __shfl_xor(p, 16, 64);
        p += __shfl_xor(p, 32, 64);
        psum[g] = p;
    }
    float* Ob = Opart + (size_t)blk * 2048;
#pragma unroll
    for (int g = 0; g < 2; ++g)
#pragma unroll
        for (int dt = 0; dt < 4; ++dt) {
            float4 o = make_float4(O[dt][g][0], O[dt][g][1], O[dt][g][2], O[dt][g][3]);
            *(float4*)(Ob + (g * 16 + l16) * 64 + dt * 16 + quad * 4) = o;
        }
    if (quad == 0) {
        Lbuf[blk * 32 + l16] = psum[0];
        Lbuf[blk * 32 + 16 + l16] = psum[1];
    }
}

// ---- output projection (MFMA) with trivial split-K combine (weights all 1)
__global__ __launch_bounds__(128) void oproj_kernel(
    const float* __restrict__ Opart, const float* __restrict__ Lbuf,
    const unsigned short* __restrict__ Wt, const float* __restrict__ bo,
    float* __restrict__ out)
{
    const int b = blockIdx.x;
    const int t = threadIdx.x, w = t >> 6, lane = t & 63;
    const int quad = lane >> 4, l16 = lane & 15;
    const int n0 = (b >> 1) * 16, colbase = (b & 1) * 128 + w * 64;
    v4f acc[4];
#pragma unroll
    for (int ct = 0; ct < 4; ++ct) {
        const float bb = bo[colbase + ct * 16 + l16];
        acc[ct] = v4f{bb, bb, bb, bb};
    }
    const int n = n0 + l16;
    const int qta = n >> 5, rl = n & 31;
#pragma unroll
    for (int hh = 0; hh < 4; ++hh) {
        const int blk0 = qta * 16 + hh * 4;
        const float lsum = Lbuf[(blk0 + 0) * 32 + rl] + Lbuf[(blk0 + 1) * 32 + rl]
                         + Lbuf[(blk0 + 2) * 32 + rl] + Lbuf[(blk0 + 3) * 32 + rl];
        const float linv = 1.f / lsum;
#pragma unroll
        for (int kh = 0; kh < 2; ++kh) {
            const int d0 = kh * 32 + quad * 8;
            float a[8];
#pragma unroll
            for (int g = 0; g < 2; ++g) {
                const float4 x0 = *(const float4*)(Opart + (size_t)(blk0 + 0) * 2048 + rl * 64 + d0 + g * 4);
                const float4 x1 = *(const float4*)(Opart + (size_t)(blk0 + 1) * 2048 + rl * 64 + d0 + g * 4);
                const float4 x2 = *(const float4*)(Opart + (size_t)(blk0 + 2) * 2048 + rl * 64 + d0 + g * 4);
                const float4 x3 = *(const float4*)(Opart + (size_t)(blk0 + 3) * 2048 + rl * 64 + d0 + g * 4);
                a[g * 4 + 0] = ((x0.x + x1.x) + (x2.x + x3.x)) * linv;
                a[g * 4 + 1] = ((x0.y + x1.y) + (x2.y + x3.y)) * linv;
                a[g * 4 + 2] = ((x0.z + x1.z) + (x2.z + x3.z)) * linv;
                a[g * 4 + 3] = ((x0.w + x1.w) + (x2.w + x3.w)) * linv;
            }
            v8s ah, al;
            split8(a, ah, al);
#pragma unroll
            for (int ct = 0; ct < 4; ++ct) {
                const unsigned short* wp = Wt + (size_t)(colbase + ct * 16 + l16) * 256 + hh * 64 + kh * 32 + quad * 8;
                const v8s wh = *(const v8s*)wp;
                const v8s wl = *(const v8s*)(wp + 65536);
                acc[ct] = __builtin_amdgcn_mfma_f32_16x16x32_bf16(al, wh, acc[ct], 0, 0, 0);
                acc[ct] = __builtin_amdgcn_mfma_f32_16x16x32_bf16(ah, wl, acc[ct], 0, 0, 0);
                acc[ct] = __builtin_amdgcn_mfma_f32_16x16x32_bf16(ah, wh, acc[ct], 0, 0, 0);
            }
        }
    }
#pragma unroll
    for (int ct = 0; ct < 4; ++ct)
#pragma unroll
        for (int r = 0; r < 4; ++r)
            out[(size_t)(n0 + quad * 4 + r) * 256 + colbase + ct * 16 + l16] = acc[ct][r];
}

extern "C" void kernel_launch(void* const* d_in, const int* in_sizes, int n_in,
                              void* d_out, int out_size, void* d_ws, size_t ws_size,
                              hipStream_t stream) {
    const float* query = (const float*)d_in[0];
    const float* key   = (const float*)d_in[1];
    const float* value = (const float*)d_in[2];
    const float* Wq    = (const float*)d_in[3];
    const float* bq    = (const float*)d_in[4];
    const float* Wk    = (const float*)d_in[5];
    const float* bk    = (const float*)d_in[6];
    const float* Wv    = (const float*)d_in[7];
    const float* bv    = (const float*)d_in[8];
    const float* Wo    = (const float*)d_in[9];
    const float* bo    = (const float*)d_in[10];
    const int*   nex   = (const int*)d_in[11];

    char* ws = (char*)d_ws;
    unsigned short* Qb  = (unsigned short*)(ws);                               // 2 MB
    unsigned short* Kb  = (unsigned short*)(ws + (size_t)2  * 1024 * 1024);    // 4 MB
    unsigned short* Vt  = (unsigned short*)(ws + (size_t)6  * 1024 * 1024);    // 4 MB
    float* Opart        = (float*)(ws + (size_t)10 * 1024 * 1024);             // 16 MB
    float* Lbuf         = (float*)(ws + (size_t)26 * 1024 * 1024);             // 256 KB
    char* wbase         = ws + (size_t)26 * 1024 * 1024 + 512 * 1024;
    unsigned short* Wqt = (unsigned short*)(wbase);                            // 256 KB
    unsigned short* Wkt = (unsigned short*)(wbase + 256 * 1024);               // 64 KB
    unsigned short* Wvt = (unsigned short*)(wbase + 320 * 1024);               // 64 KB
    unsigned short* Wot = (unsigned short*)(wbase + 384 * 1024);               // 256 KB
    float* out          = (float*)d_out;

    wprep_kernel<<<640, 256, 0, stream>>>(Wq, Wk, Wv, Wo, Wqt, Wkt, Wvt, Wot);
    qkv_kernel<<<2560, 128, 0, stream>>>(query, key, value, Wqt, Wkt, Wvt,
                                         bq, bk, bv, Qb, Kb, Vt, nex);
    attn_kernel<<<2048, 64, 0, stream>>>(Qb, Kb, Vt, Opart, Lbuf);
    oproj_kernel<<<512, 128, 0, stream>>>(Opart, Lbuf, Wot, bo, out);
}

// Round 5
// 180.195 us; speedup vs baseline: 1.3215x; 1.3215x over previous
//
#include <hip/hip_runtime.h>
#include <hip/hip_bf16.h>

#define H 4
#define NQ 4096
#define NK 8192
#define D 64
#define BK 64
#define NSPLIT 8
#define KSPAN (NK / NSPLIT)
#define PST 72

// 0.125 (1/sqrt(64)) * log2(e): scores in log2 domain; no max subtraction needed
// (|S| <= ~14 so exp2(S) <= 2^14, l <= 2^27 — no overflow; scale cancels in O/l)
#define QSCALE 0.1803368801111204f

typedef short v8s __attribute__((ext_vector_type(8)));
typedef float v4f __attribute__((ext_vector_type(4)));

static __device__ __forceinline__ unsigned short f2bf(float f) {
    unsigned int u = __float_as_uint(f);
    u = (u + 0x7FFFu + ((u >> 16) & 1u)) >> 16;
    return (unsigned short)u;
}
static __device__ __forceinline__ float bf2f(unsigned short h) {
    return __uint_as_float(((unsigned int)h) << 16);
}
static __device__ __forceinline__ unsigned int pkbf(float a, float b) {
    union { __hip_bfloat162 h; unsigned int u; } cv;
    cv.h = __float22bfloat162_rn(make_float2(a, b));
    return cv.u;
}
static __device__ __forceinline__ void split8(const float* a, v8s& hi, v8s& lo) {
#pragma unroll
    for (int j = 0; j < 8; ++j) {
        unsigned short h = f2bf(a[j]);
        hi[j] = (short)h;
        lo[j] = (short)f2bf(a[j] - bf2f(h));
    }
}
// async global->LDS, 16B/lane; dest = uniform base + lane*16
static __device__ __forceinline__ void dma16(const unsigned short* g, unsigned short* l) {
    __builtin_amdgcn_global_load_lds(
        (const __attribute__((address_space(1))) unsigned int*)(const void*)g,
        (__attribute__((address_space(3))) unsigned int*)(void*)l, 16, 0, 0);
}

// ---- W prep: bf16 hi/lo planes, TRANSPOSED [col][k]
__global__ __launch_bounds__(256) void wprep_kernel(
    const float* __restrict__ Wq, const float* __restrict__ Wk,
    const float* __restrict__ Wv, const float* __restrict__ Wo,
    unsigned short* __restrict__ Wqt, unsigned short* __restrict__ Wkt,
    unsigned short* __restrict__ Wvt, unsigned short* __restrict__ Wot)
{
    int i = blockIdx.x * 256 + threadIdx.x;
    const float* src; unsigned short* dst; int idx, sh;
    if (i < 65536)       { src = Wq; dst = Wqt; idx = i;          sh = 8; }
    else if (i < 81920)  { src = Wk; dst = Wkt; idx = i - 65536;  sh = 6; }
    else if (i < 98304)  { src = Wv; dst = Wvt; idx = i - 81920;  sh = 6; }
    else                 { src = Wo; dst = Wot; idx = i - 98304;  sh = 8; }
    const int K = 1 << sh;
    const int c = idx >> sh, e = idx & (K - 1);
    const float v = src[e * 256 + c];
    const unsigned short h = f2bf(v);
    dst[idx] = h;
    dst[idx + (K << 8)] = f2bf(v - bf2f(h));
}

// ---- fused QKV projection: b<128 Q(32 rows), b<384 K, else V. 256 thr, wave=head.
__global__ __launch_bounds__(256) void qkv_kernel(
    const float* __restrict__ query, const float* __restrict__ key,
    const float* __restrict__ value,
    const unsigned short* __restrict__ Wqt, const unsigned short* __restrict__ Wkt,
    const unsigned short* __restrict__ Wvt,
    const float* __restrict__ bq, const float* __restrict__ bk,
    const float* __restrict__ bv,
    unsigned short* __restrict__ Qb, unsigned short* __restrict__ Kb,
    unsigned short* __restrict__ Vt, const int* __restrict__ nexp)
{
    const int b = blockIdx.x;
    const int t = threadIdx.x, w = t >> 6, lane = t & 63;
    const int quad = lane >> 4, l16 = lane & 15;
    const int colbase = w * 64;

    if (b < 128) {
        // ---- Q: KD=256
        const int n0 = b * 32;
        v4f acc[2][4];
#pragma unroll
        for (int st = 0; st < 2; ++st)
#pragma unroll
            for (int ct = 0; ct < 4; ++ct) {
                const float bb = bq[colbase + ct * 16 + l16];
                acc[st][ct] = v4f{bb, bb, bb, bb};
            }
#pragma unroll
        for (int k0 = 0; k0 < 256; k0 += 32) {
            v8s ah[2], al[2];
#pragma unroll
            for (int st = 0; st < 2; ++st) {
                float av[8];
                const float* ar = query + (size_t)(n0 + st * 16 + l16) * 256 + k0 + quad * 8;
                *(float4*)av = *(const float4*)ar;
                *(float4*)(av + 4) = *(const float4*)(ar + 4);
                split8(av, ah[st], al[st]);
            }
#pragma unroll
            for (int ct = 0; ct < 4; ++ct) {
                const unsigned short* wp = Wqt + (size_t)(colbase + ct * 16 + l16) * 256 + k0 + quad * 8;
                const v8s wh = *(const v8s*)wp;
                const v8s wl = *(const v8s*)(wp + 65536);
#pragma unroll
                for (int st = 0; st < 2; ++st) {
                    acc[st][ct] = __builtin_amdgcn_mfma_f32_16x16x32_bf16(al[st], wh, acc[st][ct], 0, 0, 0);
                    acc[st][ct] = __builtin_amdgcn_mfma_f32_16x16x32_bf16(ah[st], wl, acc[st][ct], 0, 0, 0);
                    acc[st][ct] = __builtin_amdgcn_mfma_f32_16x16x32_bf16(ah[st], wh, acc[st][ct], 0, 0, 0);
                }
            }
        }
#pragma unroll
        for (int ct = 0; ct < 4; ++ct) {
            const int d = ct * 16 + l16;
            const int j = d >> 1;
            const float freq = exp2f(-(float)(j & 15) * 1.66096404744368f);
            const bool isx = (j < 16), odd = (d & 1);
#pragma unroll
            for (int st = 0; st < 2; ++st)
#pragma unroll
                for (int r = 0; r < 4; ++r) {
                    const int p = n0 + st * 16 + quad * 4 + r;
                    const float tpos = isx ? (float)(p & 63) : (float)(p >> 6);
                    float sn, cs;
                    __sincosf(tpos * freq, &sn, &cs);
                    const float x = acc[st][ct][r];
                    const float xp = __shfl_xor(x, 1, 64);
                    const float y = odd ? fmaf(x, cs, xp * sn) : fmaf(x, cs, -xp * sn);
                    Qb[((size_t)(w * NQ + p) << 6) + d] = f2bf(y * QSCALE);
                }
        }
    } else {
        const bool isK = (b < 384);
        const int n0 = (isK ? (b - 128) : (b - 384)) * 32;
        const float* X = isK ? key : value;
        const unsigned short* Wt = isK ? Wkt : Wvt;
        const float* bias = isK ? bk : bv;
        // preload all W frags (KD=64): 16 v8s
        v8s wf[4][2][2];
#pragma unroll
        for (int ct = 0; ct < 4; ++ct)
#pragma unroll
            for (int k = 0; k < 2; ++k) {
                const unsigned short* wp = Wt + (size_t)(colbase + ct * 16 + l16) * 64 + k * 32 + quad * 8;
                wf[ct][k][0] = *(const v8s*)wp;
                wf[ct][k][1] = *(const v8s*)(wp + 16384);
            }
        v4f acc[2][4];
#pragma unroll
        for (int st = 0; st < 2; ++st)
#pragma unroll
            for (int ct = 0; ct < 4; ++ct) {
                const float bb = bias[colbase + ct * 16 + l16];
                acc[st][ct] = v4f{bb, bb, bb, bb};
            }
#pragma unroll
        for (int st = 0; st < 2; ++st)
#pragma unroll
            for (int k = 0; k < 2; ++k) {
                float av[8];
                const float* ar = X + (size_t)(n0 + st * 16 + l16) * 64 + k * 32 + quad * 8;
                *(float4*)av = *(const float4*)ar;
                *(float4*)(av + 4) = *(const float4*)(ar + 4);
                v8s ah, al;
                split8(av, ah, al);
#pragma unroll
                for (int ct = 0; ct < 4; ++ct) {
                    acc[st][ct] = __builtin_amdgcn_mfma_f32_16x16x32_bf16(al, wf[ct][k][0], acc[st][ct], 0, 0, 0);
                    acc[st][ct] = __builtin_amdgcn_mfma_f32_16x16x32_bf16(ah, wf[ct][k][1], acc[st][ct], 0, 0, 0);
                    acc[st][ct] = __builtin_amdgcn_mfma_f32_16x16x32_bf16(ah, wf[ct][k][0], acc[st][ct], 0, 0, 0);
                }
            }
        if (isK) {
            const int nro = NK - *nexp;
#pragma unroll
            for (int ct = 0; ct < 4; ++ct) {
                const int d = ct * 16 + l16;
                const int j = d >> 1;
                const float freq = exp2f(-(float)(j & 15) * 1.66096404744368f);
                const bool isx = (j < 16), odd = (d & 1);
#pragma unroll
                for (int st = 0; st < 2; ++st)
#pragma unroll
                    for (int r = 0; r < 4; ++r) {
                        const int p = n0 + st * 16 + quad * 4 + r;
                        const int pc = p & 4095;
                        const float tpos = isx ? (float)(pc & 63) : (float)(pc >> 6);
                        float sn, cs;
                        __sincosf(tpos * freq, &sn, &cs);
                        const float x = acc[st][ct][r];
                        const float xp = __shfl_xor(x, 1, 64);
                        float y = odd ? fmaf(x, cs, xp * sn) : fmaf(x, cs, -xp * sn);
                        y = (p < nro) ? y : x;
                        Kb[((size_t)(w * NK + p) << 6) + d] = f2bf(y);
                    }
            }
        } else {
#pragma unroll
            for (int ct = 0; ct < 4; ++ct) {
                const int col = colbase + ct * 16 + l16;
#pragma unroll
                for (int st = 0; st < 2; ++st) {
                    uint2 u = make_uint2(pkbf(acc[st][ct][0], acc[st][ct][1]),
                                         pkbf(acc[st][ct][2], acc[st][ct][3]));
                    *(uint2*)(Vt + (size_t)col * NK + n0 + st * 16 + quad * 4) = u;
                }
            }
        }
    }
}

// ---- flash attention: 1024 blocks = qt(32) x h(4) x s(8); 4 waves x 32 q-rows
// lds-dma staged K/V with XOR chunk swizzle; no-max softmax; P per-wave LDS
__global__ __launch_bounds__(256) void attn_kernel(
    const unsigned short* __restrict__ Qb, const unsigned short* __restrict__ Kb,
    const unsigned short* __restrict__ Vt, unsigned short* __restrict__ Opart,
    float* __restrict__ Lbuf)
{
    __shared__ alignas(16) unsigned short Kl[64 * 64];
    __shared__ alignas(16) unsigned short Vl[64 * 64];
    __shared__ alignas(16) unsigned short Pl[4 * 32 * PST];

    const int blk = blockIdx.x;
    const int s = blk & 7, h = (blk >> 3) & 3, qt = blk >> 5;
    const int t = threadIdx.x;
    const int w = t >> 6, lane = t & 63;
    const int quad = lane >> 4, l16 = lane & 15;

    const int q0 = qt * 128 + w * 32;
    v8s qf[2][2];
#pragma unroll
    for (int g = 0; g < 2; ++g) {
        const unsigned short* qr = Qb + ((size_t)(h * NQ + q0 + g * 16 + l16) << 6) + quad * 8;
        qf[g][0] = *(const v8s*)qr;
        qf[g][1] = *(const v8s*)(qr + 32);
    }

    v4f O[4][2];
#pragma unroll
    for (int dt = 0; dt < 4; ++dt)
#pragma unroll
        for (int g = 0; g < 2; ++g) O[dt][g] = v4f{0.f, 0.f, 0.f, 0.f};
    float psum[2] = {0.f, 0.f};

    const unsigned short* Kbase = Kb + (((size_t)h * NK + s * KSPAN) << 6);
    const unsigned short* Vbase = Vt + (size_t)(h * 64) * NK + s * KSPAN;

    // staging lane geometry (swizzle: chunk ^= row&7; rows 8/instr so row&7 = lane>>3)
    const int srow = lane >> 3;                 // 0..7
    const int schunk = (lane & 7) ^ srow;       // swizzled 16B chunk
    // reader chunk offsets (shorts): c0 = quad ^ (l16&7)
    const int c0off = ((quad ^ (l16 & 7)) * 8);
    const int c1off = c0off ^ 32;
    unsigned short* Pw = &Pl[w * 32 * PST];

    for (int k0 = 0; k0 < KSPAN; k0 += BK) {
        __syncthreads();
#pragma unroll
        for (int half = 0; half < 2; ++half) {
            const int r0 = w * 16 + half * 8;
            dma16(Kbase + ((size_t)(k0 + r0 + srow) << 6) + schunk * 8, &Kl[r0 * 64]);
            dma16(Vbase + (size_t)(r0 + srow) * NK + k0 + schunk * 8, &Vl[r0 * 64]);
        }
        __syncthreads();

        // S^T = K Q^T ; immediately exp2 (no max) and stash P[q][k] per-wave
#pragma unroll
        for (int tt = 0; tt < 4; ++tt) {
            const unsigned short* kr = &Kl[(tt * 16 + l16) * 64];
            const v8s kf0 = *(const v8s*)(kr + c0off);
            const v8s kf1 = *(const v8s*)(kr + c1off);
#pragma unroll
            for (int g = 0; g < 2; ++g) {
                v4f a = v4f{0.f, 0.f, 0.f, 0.f};
                a = __builtin_amdgcn_mfma_f32_16x16x32_bf16(kf0, qf[g][0], a, 0, 0, 0);
                a = __builtin_amdgcn_mfma_f32_16x16x32_bf16(kf1, qf[g][1], a, 0, 0, 0);
                const float e0 = __builtin_amdgcn_exp2f(a[0]);
                const float e1 = __builtin_amdgcn_exp2f(a[1]);
                const float e2 = __builtin_amdgcn_exp2f(a[2]);
                const float e3 = __builtin_amdgcn_exp2f(a[3]);
                psum[g] += (e0 + e1) + (e2 + e3);
                *(uint2*)(&Pw[(g * 16 + l16) * PST + tt * 16 + quad * 4]) =
                    make_uint2(pkbf(e0, e1), pkbf(e2, e3));
            }
        }
        __asm__ volatile("s_waitcnt lgkmcnt(0)" ::: "memory");

        v8s pf[2][2];
#pragma unroll
        for (int g = 0; g < 2; ++g) {
            const unsigned short* pr = &Pw[(g * 16 + l16) * PST + quad * 8];
            pf[g][0] = *(const v8s*)pr;
            pf[g][1] = *(const v8s*)(pr + 32);
        }
#pragma unroll
        for (int dt = 0; dt < 4; ++dt) {
            const unsigned short* vr = &Vl[(dt * 16 + l16) * 64];
            const v8s vf0 = *(const v8s*)(vr + c0off);
            const v8s vf1 = *(const v8s*)(vr + c1off);
#pragma unroll
            for (int g = 0; g < 2; ++g) {
                v4f a = O[dt][g];
                a = __builtin_amdgcn_mfma_f32_16x16x32_bf16(vf0, pf[g][0], a, 0, 0, 0);
                a = __builtin_amdgcn_mfma_f32_16x16x32_bf16(vf1, pf[g][1], a, 0, 0, 0);
                O[dt][g] = a;
            }
        }
    }

#pragma unroll
    for (int g = 0; g < 2; ++g) {
        float p = psum[g];
        p += __shfl_xor(p, 16, 64);
        p += __shfl_xor(p, 32, 64);
        psum[g] = p;
    }
    unsigned short* Ob = Opart + (size_t)blk * 8192;
#pragma unroll
    for (int g = 0; g < 2; ++g) {
        const int row = w * 32 + g * 16 + l16;
#pragma unroll
        for (int dt = 0; dt < 4; ++dt) {
            uint2 u = make_uint2(pkbf(O[dt][g][0], O[dt][g][1]),
                                 pkbf(O[dt][g][2], O[dt][g][3]));
            *(uint2*)(Ob + row * 64 + dt * 16 + quad * 4) = u;
        }
        if (quad == 0) Lbuf[blk * 128 + row] = psum[g];
    }
}

// ---- output projection: MFMA bf16 partials directly (split-sum is linear),
// per-head 1/l applied between head chunks. 256 blocks x 256 thr.
__global__ __launch_bounds__(256) void oproj_kernel(
    const unsigned short* __restrict__ Opart, const float* __restrict__ Lbuf,
    const unsigned short* __restrict__ Wt, const float* __restrict__ bo,
    float* __restrict__ out)
{
    const int t = threadIdx.x, w = t >> 6, lane = t & 63;
    const int quad = lane >> 4, l16 = lane & 15;
    const int n0 = blockIdx.x * 16, colbase = w * 64;
    const int qt = n0 >> 7, rbase = n0 & 127;

    v4f facc[4];
#pragma unroll
    for (int ct = 0; ct < 4; ++ct) facc[ct] = v4f{0.f, 0.f, 0.f, 0.f};

#pragma unroll 1
    for (int hh = 0; hh < 4; ++hh) {
        v8s wfr[4][2][2];
#pragma unroll
        for (int ct = 0; ct < 4; ++ct)
#pragma unroll
            for (int ch = 0; ch < 2; ++ch) {
                const unsigned short* wp = Wt + (size_t)(colbase + ct * 16 + l16) * 256 + hh * 64 + ch * 32 + quad * 8;
                wfr[ct][ch][0] = *(const v8s*)wp;
                wfr[ct][ch][1] = *(const v8s*)(wp + 65536);
            }
        v4f hacc[4];
#pragma unroll
        for (int ct = 0; ct < 4; ++ct) hacc[ct] = v4f{0.f, 0.f, 0.f, 0.f};
        float4 lsum = make_float4(0.f, 0.f, 0.f, 0.f);
#pragma unroll
        for (int sp = 0; sp < NSPLIT; ++sp) {
            const int slab = (qt * 4 + hh) * 8 + sp;
            const unsigned short* arow = Opart + (size_t)slab * 8192 + (rbase + l16) * 64;
#pragma unroll
            for (int ch = 0; ch < 2; ++ch) {
                const v8s A = *(const v8s*)(arow + ch * 32 + quad * 8);
#pragma unroll
                for (int ct = 0; ct < 4; ++ct) {
                    hacc[ct] = __builtin_amdgcn_mfma_f32_16x16x32_bf16(A, wfr[ct][ch][0], hacc[ct], 0, 0, 0);
                    hacc[ct] = __builtin_amdgcn_mfma_f32_16x16x32_bf16(A, wfr[ct][ch][1], hacc[ct], 0, 0, 0);
                }
            }
            const float4 lv = *(const float4*)(Lbuf + slab * 128 + rbase + quad * 4);
            lsum.x += lv.x; lsum.y += lv.y; lsum.z += lv.z; lsum.w += lv.w;
        }
        const float li[4] = {1.f / lsum.x, 1.f / lsum.y, 1.f / lsum.z, 1.f / lsum.w};
#pragma unroll
        for (int ct = 0; ct < 4; ++ct)
#pragma unroll
            for (int r = 0; r < 4; ++r)
                facc[ct][r] = fmaf(hacc[ct][r], li[r], facc[ct][r]);
    }
#pragma unroll
    for (int ct = 0; ct < 4; ++ct) {
        const float bb = bo[colbase + ct * 16 + l16];
#pragma unroll
        for (int r = 0; r < 4; ++r)
            out[(size_t)(n0 + quad * 4 + r) * 256 + colbase + ct * 16 + l16] = facc[ct][r] + bb;
    }
}

extern "C" void kernel_launch(void* const* d_in, const int* in_sizes, int n_in,
                              void* d_out, int out_size, void* d_ws, size_t ws_size,
                              hipStream_t stream) {
    const float* query = (const float*)d_in[0];
    const float* key   = (const float*)d_in[1];
    const float* value = (const float*)d_in[2];
    const float* Wq    = (const float*)d_in[3];
    const float* bq    = (const float*)d_in[4];
    const float* Wk    = (const float*)d_in[5];
    const float* bk    = (const float*)d_in[6];
    const float* Wv    = (const float*)d_in[7];
    const float* bv    = (const float*)d_in[8];
    const float* Wo    = (const float*)d_in[9];
    const float* bo    = (const float*)d_in[10];
    const int*   nex   = (const int*)d_in[11];

    char* ws = (char*)d_ws;
    unsigned short* Qb  = (unsigned short*)(ws);                               // 2 MB
    unsigned short* Kb  = (unsigned short*)(ws + (size_t)2  * 1024 * 1024);    // 4 MB
    unsigned short* Vt  = (unsigned short*)(ws + (size_t)6  * 1024 * 1024);    // 4 MB
    unsigned short* Opart = (unsigned short*)(ws + (size_t)10 * 1024 * 1024);  // 16 MB bf16
    float* Lbuf         = (float*)(ws + (size_t)26 * 1024 * 1024);             // 512 KB
    char* wbase         = ws + (size_t)26 * 1024 * 1024 + 512 * 1024;
    unsigned short* Wqt = (unsigned short*)(wbase);                            // 256 KB
    unsigned short* Wkt = (unsigned short*)(wbase + 256 * 1024);               // 64 KB
    unsigned short* Wvt = (unsigned short*)(wbase + 320 * 1024);               // 64 KB
    unsigned short* Wot = (unsigned short*)(wbase + 384 * 1024);               // 256 KB
    float* out          = (float*)d_out;

    wprep_kernel<<<640, 256, 0, stream>>>(Wq, Wk, Wv, Wo, Wqt, Wkt, Wvt, Wot);
    qkv_kernel<<<640, 256, 0, stream>>>(query, key, value, Wqt, Wkt, Wvt,
                                        bq, bk, bv, Qb, Kb, Vt, nex);
    attn_kernel<<<1024, 256, 0, stream>>>(Qb, Kb, Vt, Opart, Lbuf);
    oproj_kernel<<<256, 256, 0, stream>>>(Opart, Lbuf, Wot, bo, out);
}